// Round 9
// baseline (248.653 us; speedup 1.0000x reference)
//
#include <hip/hip_runtime.h>

#define PH 512
#define PW 512
#define PLANE (PH * PW)
#define RS 68 /* V-window row stride (floats): conflict-free column reads */
#define PHYS(i) (((i) & 7) * 70 + ((i) >> 3)) /* hpass staged-row swizzle */

enum { V_F0 = 0, V_MID = 1, V_L3D = 2, V_MONLY = 3 };

// ---- compile-time Gaussian weights (literal constants in the ISA) ---------
constexpr double cexp_pos(double z) { // exp(z), z >= 0, Taylor series
  double term = 1.0, sum = 1.0;
  for (int k = 1; k < 160; ++k) {
    term *= z / (double)k;
    sum += term;
  }
  return sum;
}
template <int LVL, int R>
struct WTab {
  float w[2 * R + 1];
  constexpr WTab() : w{} {
    double sig = 1.0;
    for (int i = 0; i < LVL; ++i) sig *= 2.0;
    double g[2 * R + 1] = {};
    double s = 0.0;
    for (int t = 0; t <= 2 * R; ++t) {
      double x = (double)(t - R);
      g[t] = 1.0 / cexp_pos((x * x) / (2.0 * sig * sig));
      s += g[t];
    }
    for (int t = 0; t <= 2 * R; ++t) w[t] = (float)(g[t] / s);
  }
};

__device__ __forceinline__ int clampi(int v, int hi) {
  return v < 0 ? 0 : (v > hi ? hi : v);
}
// XCD-aware bijective chunked swizzle (all grids here are multiples of 8)
__device__ __forceinline__ int swz(int bid, int nwg) {
  const int q = nwg >> 3;
  return (bid & 7) * q + (bid >> 3);
}
__device__ __forceinline__ float bf2f(ushort s) {
  return __uint_as_float((unsigned)s << 16);
}
__device__ __forceinline__ ushort f2bf(float f) { // RNE
  unsigned x = __float_as_uint(f);
  return (ushort)((x + 0x7FFF + ((x >> 16) & 1)) >> 16);
}
union BU { uint4 q; ushort u[8]; };
__device__ __forceinline__ void ldb8(const ushort* __restrict__ p, float* v) {
  BU b;
  b.q = *(const uint4*)p;
#pragma unroll
  for (int j = 0; j < 8; ++j) v[j] = bf2f(b.u[j]);
}
__device__ __forceinline__ void stb8(ushort* __restrict__ p, const float* v) {
  BU b;
#pragma unroll
  for (int j = 0; j < 8; ++j) b.u[j] = f2bf(v[j]);
  *(uint4*)p = b.q;
}
__device__ __forceinline__ void ldf8(const float* __restrict__ p, float* v) {
  float4 a = *(const float4*)p, b = *(const float4*)(p + 4);
  v[0] = a.x; v[1] = a.y; v[2] = a.z; v[3] = a.w;
  v[4] = b.x; v[5] = b.y; v[6] = b.z; v[7] = b.w;
}
__device__ __forceinline__ void stf8(float* __restrict__ p, const float* v) {
  *(float4*)p = make_float4(v[0], v[1], v[2], v[3]);
  *(float4*)(p + 4) = make_float4(v[4], v[5], v[6], v[7]);
}
__device__ __forceinline__ void q2f8(uint4 q, float* v) {
  BU b;
  b.q = q;
#pragma unroll
  for (int j = 0; j < 8; ++j) v[j] = bf2f(b.u[j]);
}
__device__ __forceinline__ void ff2f8(float4 a, float4 b, float* v) {
  v[0] = a.x; v[1] = a.y; v[2] = a.z; v[3] = a.w;
  v[4] = b.x; v[5] = b.y; v[6] = b.z; v[7] = b.w;
}

// ---------------- horizontal pass ------------------------------------------
// block = 256 = 4 rows x 64 lanes; each lane produces 8 consecutive x.
template <int LVL, int R, bool LV0>
__global__ __launch_bounds__(256) void hpass_tele(
    const ushort* __restrict__ S, const float* __restrict__ in0,
    const float* __restrict__ in1, const float* __restrict__ inm,
    ushort* __restrict__ tmp, int cn3) {
  constexpr WTab<LVL, R> W;
  const int bid = swz(blockIdx.x, gridDim.x);
  const int tid = threadIdx.x;
  const int ry = tid >> 6, lr = tid & 63;
  const int p = bid >> 7;
  const int y = ((bid & 127) << 2) + ry;
  const int xb = lr << 3;

  __shared__ float lds[4][8 * 70];
  float* L = lds[ry];

  if (LV0) {
    if (p < cn3) {
      const float* rA = in0 + (size_t)p * PLANE + (size_t)y * PW;
      const float* rB = in1 + (size_t)p * PLANE + (size_t)y * PW;
      float a8[8], b8[8];
      ldf8(rA + xb, a8);
      ldf8(rB + xb, b8);
#pragma unroll
      for (int k = 0; k < 8; ++k) L[PHYS(R + xb + k)] = b8[k] - a8[k];
      if (lr < R) L[PHYS(lr)] = rB[0] - rA[0];
      else if (lr >= 32 && lr < 32 + R)
        L[PHYS(R + PW + (lr - 32))] = rB[PW - 1] - rA[PW - 1];
    } else {
      const float* rM = inm + (size_t)(p - cn3) * PLANE + (size_t)y * PW;
      float a8[8];
      ldf8(rM + xb, a8);
#pragma unroll
      for (int k = 0; k < 8; ++k) L[PHYS(R + xb + k)] = a8[k];
      if (lr < R) L[PHYS(lr)] = rM[0];
      else if (lr >= 32 && lr < 32 + R)
        L[PHYS(R + PW + (lr - 32))] = rM[PW - 1];
    }
  } else {
    const ushort* row = S + (size_t)p * PLANE + (size_t)y * PW;
    float a8[8];
    ldb8(row + xb, a8);
#pragma unroll
    for (int k = 0; k < 8; ++k) L[PHYS(R + xb + k)] = a8[k];
    if (lr < R) L[PHYS(lr)] = bf2f(row[0]);
    else if (lr >= 32 && lr < 32 + R)
      L[PHYS(R + PW + (lr - 32))] = bf2f(row[PW - 1]);
  }
  __syncthreads();

  float a[8];
#pragma unroll
  for (int i = 0; i < 8; ++i) a[i] = 0.f;
#pragma unroll
  for (int j = 0; j < 2 * R + 8; ++j) {
    const float v = L[PHYS(xb + j)];
#pragma unroll
    for (int i = 0; i < 8; ++i)
      if (i <= j && j - i <= 2 * R) a[i] = fmaf(W.w[j - i], v, a[i]);
  }
  stb8(tmp + (size_t)p * PLANE + (size_t)y * PW + xb, a);
}

// ---------------- vertical pass + telescoped epilogue ----------------------
// block = 512 thr, 64x64 output tile. T14 async-stage: all epilogue global
// streams are issued as RAW vector loads at kernel entry (4-8 VGPR each);
// their HBM latency hides under window-load + conv + transpose. Converted
// only at use. __launch_bounds__(512,8) keeps VGPR<=64 -> 4 blocks/CU.
template <int LVL, int R, int MODE>
__global__ __launch_bounds__(512, 8) void vpass_tele(
    const ushort* __restrict__ tmp, const ushort* __restrict__ Sc,
    const ushort* __restrict__ Sm, const ushort* __restrict__ Gm4,
    const float* __restrict__ in0, const float* __restrict__ in1,
    const float* __restrict__ inm, ushort* __restrict__ oS,
    ushort* __restrict__ oM, float* __restrict__ outp, int cn3) {
  constexpr WTab<LVL, R> W;
  constexpr int VWIN = 64 + 2 * R;
  __shared__ float buf[VWIN * RS];
  const int bid = swz(blockIdx.x, gridDim.x);
  const int tid = threadIdx.x;
  const int lane = tid & 63, yg = tid >> 6;
  const int p = bid >> 6, t = bid & 63;
  const int x0 = (t & 7) << 6, y0 = (t >> 3) << 6;
  const int ey = tid >> 3, exq = (tid & 7) << 3;
  const size_t erow = (size_t)(y0 + ey) * PW + x0 + exq;

  const bool ismask = (MODE == V_MONLY) || (MODE != V_L3D && p >= cn3);
  const int pm = ismask ? ((MODE == V_MONLY) ? p : p - cn3) : 0;
  const int n = p / 3;

  // ---- T14 prefetch: issue epilogue streams NOW, consume at the end ----
  float4 f0a{}, f0b{}, f1a{}, f1b{}, fma_{}, fmb_{}; // V_F0 (f32)
  uint4 qSc{}, qSm{}, qGm4{};                        // bf16 streams
  float4 qpa{}, qpb{};                               // out RMW (f32)
  if (!ismask) {
    if (MODE == V_F0) {
      const float* p0 = in0 + (size_t)p * PLANE + erow;
      const float* p1 = in1 + (size_t)p * PLANE + erow;
      const float* pmk = inm + (size_t)n * PLANE + erow;
      f0a = *(const float4*)p0;       f0b = *(const float4*)(p0 + 4);
      f1a = *(const float4*)p1;       f1b = *(const float4*)(p1 + 4);
      fma_ = *(const float4*)pmk;     fmb_ = *(const float4*)(pmk + 4);
    } else {
      qSc = *(const uint4*)(Sc + (size_t)p * PLANE + erow);
      qSm = *(const uint4*)(Sm + (size_t)n * PLANE + erow);
      if (MODE == V_L3D) qGm4 = *(const uint4*)(Gm4 + (size_t)n * PLANE + erow);
      const float* op = outp + (size_t)p * PLANE + erow;
      qpa = *(const float4*)op;       qpb = *(const float4*)(op + 4);
    }
  }

  // ---- load vertical window (bf16 -> f32 LDS, 16B granules) ----
  {
    const ushort* src = tmp + (size_t)(ismask ? (cn3 + pm) : p) * PLANE;
    for (int idx = tid; idx < VWIN * 8; idx += 512) {
      const int row = idx >> 3, c8 = (idx & 7) << 3;
      const int gy = clampi(y0 + row - R, PH - 1);
      BU b;
      b.q = *(const uint4*)&src[(size_t)gy * PW + x0 + c8];
      float* d = &buf[row * RS + c8];
#pragma unroll
      for (int j = 0; j < 8; ++j) d[j] = bf2f(b.u[j]);
    }
  }
  __syncthreads();

  // ---- V conv: stream-form, 8 consecutive rows at column `lane` ----
  float b[8];
#pragma unroll
  for (int i = 0; i < 8; ++i) b[i] = 0.f;
#pragma unroll
  for (int j = 0; j < 2 * R + 8; ++j) {
    const float v = buf[((yg << 3) + j) * RS + lane];
#pragma unroll
    for (int i = 0; i < 8; ++i)
      if (i <= j && j - i <= 2 * R) b[i] = fmaf(W.w[j - i], v, b[i]);
  }

  // ---- transpose stash -> each thread owns 8 consecutive x at one y ----
  __syncthreads();
#pragma unroll
  for (int i = 0; i < 8; ++i) buf[lane * 65 + (yg << 3) + i] = b[i];
  __syncthreads();
  float bs[8];
#pragma unroll
  for (int j = 0; j < 8; ++j) bs[j] = buf[(exq + j) * 65 + ey];

  if (MODE == V_MONLY || ismask) {
    stb8(oM + (size_t)pm * PLANE + erow, bs);
    return;
  }

  float o[8];
  if (MODE == V_F0) {
    float v0[8], v1[8], m[8];
    ff2f8(f0a, f0b, v0);
    ff2f8(f1a, f1b, v1);
    ff2f8(fma_, fmb_, m);
#pragma unroll
    for (int j = 0; j < 8; ++j)
      o[j] = v0[j] + m[j] * ((v1[j] - v0[j]) - bs[j]);
    stf8(outp + (size_t)p * PLANE + erow, o);
    stb8(oS + (size_t)p * PLANE + erow, bs);
  } else if (MODE == V_MID) {
    float D[8], m[8], pv[8];
    q2f8(qSc, D);
    q2f8(qSm, m);
    ff2f8(qpa, qpb, pv);
#pragma unroll
    for (int j = 0; j < 8; ++j) o[j] = pv[j] + m[j] * (D[j] - bs[j]);
    stf8(outp + (size_t)p * PLANE + erow, o);
    stb8(oS + (size_t)p * PLANE + erow, bs);
  } else { // V_L3D: out += Gm3*(D3 - D4) + Gm4*D4
    float D[8], m3[8], m4[8], pv[8];
    q2f8(qSc, D);
    q2f8(qSm, m3);
    q2f8(qGm4, m4);
    ff2f8(qpa, qpb, pv);
#pragma unroll
    for (int j = 0; j < 8; ++j)
      o[j] = pv[j] + m3[j] * (D[j] - bs[j]) + m4[j] * bs[j];
    stf8(outp + (size_t)p * PLANE + erow, o);
  }
}

// ---------------- host -----------------------------------------------------
extern "C" void kernel_launch(void* const* d_in, const int* in_sizes, int n_in,
                              void* d_out, int out_size, void* d_ws,
                              size_t ws_size, hipStream_t stream) {
  const float* img0 = (const float*)d_in[0];
  const float* img1 = (const float*)d_in[1];
  const float* mask = (const float*)d_in[2];
  float* out = (float*)d_out;

  constexpr int R0 = 6, R1 = 10, R2 = 18, R3v = 22;

  const int NTOT = 16;
  const size_t perImg = (size_t)12 * PLANE * sizeof(ushort);
  int CN = 16;
  while (CN > 1 && (size_t)CN * perImg > ws_size) CN >>= 1;

  for (int s = 0; s < NTOT; s += CN) {
    ushort* SA = (ushort*)d_ws; // [D:3CN][m:CN]
    ushort* SB = SA + (size_t)4 * CN * PLANE;
    ushort* tmp = SB + (size_t)4 * CN * PLANE;

    const float* in0 = img0 + (size_t)s * 3 * PLANE;
    const float* in1 = img1 + (size_t)s * 3 * PLANE;
    const float* inm = mask + (size_t)s * PLANE;
    float* o = out + (size_t)s * 3 * PLANE;

    const int cn3 = 3 * CN;
    ushort* SAm = SA + (size_t)cn3 * PLANE;
    ushort* SBm = SB + (size_t)cn3 * PLANE;
    const ushort* nb = nullptr;
    const float* nf = nullptr;
    const dim3 hb(256), vb(512);
    const int hg = 4 * CN * 128;
    const int vg = 4 * CN * 64;
    const int vgM = CN * 64;
    const int vgD = 3 * CN * 64;

    // L0: stage D0=in1-in0 & mask -> tmp; V: out=i0+m*(D0-D1), SA.D=D1, SA.m=Gm1
    hipLaunchKernelGGL((hpass_tele<0, R0, true>), dim3(hg), hb, 0, stream, nb,
                       in0, in1, inm, tmp, cn3);
    hipLaunchKernelGGL((vpass_tele<0, R0, V_F0>), dim3(vg), vb, 0, stream, tmp,
                       nb, nb, nb, in0, in1, inm, SA, SAm, o, cn3);
    // L1: SA -> tmp; out += Gm1*(D1-D2); SB.D=D2, SB.m=Gm2
    hipLaunchKernelGGL((hpass_tele<1, R1, false>), dim3(hg), hb, 0, stream, SA,
                       nf, nf, nf, tmp, cn3);
    hipLaunchKernelGGL((vpass_tele<1, R1, V_MID>), dim3(vg), vb, 0, stream, tmp,
                       SA, SAm, nb, nf, nf, nf, SB, SBm, o, cn3);
    // L2: SB -> tmp; out += Gm2*(D2-D3); SA.D=D3, SA.m=Gm3
    hipLaunchKernelGGL((hpass_tele<2, R2, false>), dim3(hg), hb, 0, stream, SB,
                       nf, nf, nf, tmp, cn3);
    hipLaunchKernelGGL((vpass_tele<2, R2, V_MID>), dim3(vg), vb, 0, stream, tmp,
                       SB, SBm, nb, nf, nf, nf, SA, SAm, o, cn3);
    // L3: SA -> tmp; Gm4 = V(tmp.m) -> SBm; out += Gm3*(D3-D4)+Gm4*D4
    hipLaunchKernelGGL((hpass_tele<3, R3v, false>), dim3(hg), hb, 0, stream, SA,
                       nf, nf, nf, tmp, cn3);
    hipLaunchKernelGGL((vpass_tele<3, R3v, V_MONLY>), dim3(vgM), vb, 0, stream,
                       tmp, nb, nb, nb, nf, nf, nf, (ushort*)nullptr, SBm, o,
                       cn3);
    hipLaunchKernelGGL((vpass_tele<3, R3v, V_L3D>), dim3(vgD), vb, 0, stream,
                       tmp, SA, SAm, SBm, nf, nf, nf, (ushort*)nullptr,
                       (ushort*)nullptr, o, cn3);
  }
}

// Round 10
// 239.719 us; speedup vs baseline: 1.0373x; 1.0373x over previous
//
#include <hip/hip_runtime.h>

#define PH 512
#define PW 512
#define PLANE (PH * PW)

enum { M_F0 = 0, M_MID = 1, M_MONLY = 2, M_LAST = 3 };

// ---- compile-time Gaussian weights (literal constants in the ISA) ---------
constexpr double cexp_pos(double z) { // exp(z), z >= 0, Taylor series
  double term = 1.0, sum = 1.0;
  for (int k = 1; k < 160; ++k) {
    term *= z / (double)k;
    sum += term;
  }
  return sum;
}
template <int LVL, int R>
struct WTab {
  float w[2 * R + 1];
  constexpr WTab() : w{} {
    double sig = 1.0;
    for (int i = 0; i < LVL; ++i) sig *= 2.0;
    double g[2 * R + 1] = {};
    double s = 0.0;
    for (int t = 0; t <= 2 * R; ++t) {
      double x = (double)(t - R);
      g[t] = 1.0 / cexp_pos((x * x) / (2.0 * sig * sig));
      s += g[t];
    }
    for (int t = 0; t <= 2 * R; ++t) w[t] = (float)(g[t] / s);
  }
};

__device__ __forceinline__ int clampi(int v, int hi) {
  return v < 0 ? 0 : (v > hi ? hi : v);
}
// XCD-aware bijective chunked swizzle (all grids here are multiples of 8)
__device__ __forceinline__ int swz(int bid, int nwg) {
  const int q = nwg >> 3;
  return (bid & 7) * q + (bid >> 3);
}
union HU { ushort u; _Float16 h; };
union BU { uint4 q; ushort u[8]; };
__device__ __forceinline__ float h2f(ushort s) {
  HU x; x.u = s; return (float)x.h;
}
__device__ __forceinline__ ushort f2h(float f) {
  HU x; x.h = (_Float16)f; return x.u;
}
__device__ __forceinline__ void q2f8(uint4 q, float* v) {
  BU b; b.q = q;
#pragma unroll
  for (int j = 0; j < 8; ++j) v[j] = h2f(b.u[j]);
}
__device__ __forceinline__ void sth8(ushort* __restrict__ p, const float* v) {
  BU b;
#pragma unroll
  for (int j = 0; j < 8; ++j) b.u[j] = f2h(v[j]);
  *(uint4*)p = b.q;
}
__device__ __forceinline__ void ff2f8(float4 a, float4 b, float* v) {
  v[0] = a.x; v[1] = a.y; v[2] = a.z; v[3] = a.w;
  v[4] = b.x; v[5] = b.y; v[6] = b.z; v[7] = b.w;
}
__device__ __forceinline__ void stf8(float* __restrict__ p, const float* v) {
  *(float4*)p = make_float4(v[0], v[1], v[2], v[3]);
  *(float4*)(p + 4) = make_float4(v[4], v[5], v[6], v[7]);
}

// ---------------- fully-fused per-level kernel -----------------------------
// 64x64 output tile; LDS-staged (64+2R)x(64+2R8) window; H-conv -> Hb; V-conv
// + telescoped epilogue. All LDS phases verified <=2-way banked via
// WSTR = WW+6 (== 6 mod 8) and 8-rows x 8-colgroup wave mapping.
template <int LVL, int R, int MODE>
__global__ __launch_bounds__(512) void fused_lvl(
    const ushort* __restrict__ Sc, const ushort* __restrict__ Smk,
    const ushort* __restrict__ Gm4p, const float* __restrict__ in0,
    const float* __restrict__ in1, const float* __restrict__ inm,
    ushort* __restrict__ oS, ushort* __restrict__ oM,
    ushort* __restrict__ accP, float* __restrict__ outp, int cn3) {
  constexpr WTab<LVL, R> WT;
  constexpr int R8 = ((R + 7) / 8) * 8;   // 8,16,24,24
  constexpr int WW = 64 + 2 * R8;         // 80,96,112,112
  constexpr int WSTR = WW + 6;            // 86,102,118 : == 6 mod 8
  constexpr int VWIN = 64 + 2 * R;        // 76,84,100,108
  constexpr int NCH = WW / 8;             // 10,12,14,14
  __shared__ float Wb[VWIN * WSTR];
  __shared__ float Hb[VWIN * 67];

  const int bid = swz(blockIdx.x, gridDim.x);
  const int tid = threadIdx.x;
  const int p = bid >> 6, t = bid & 63;
  const int tx = t & 7;
  const int x0 = tx << 6, y0 = (t >> 3) << 6;
  const bool edge = (tx == 0) || (tx == 7);
  const int ey = tid >> 3, exq = (tid & 7) << 3;
  const size_t erow = (size_t)(y0 + ey) * PW + x0 + exq;

  const bool ismask = (MODE == M_MONLY) || (MODE != M_LAST && p >= cn3);
  const int pm = ismask ? ((MODE == M_MONLY) ? p : p - cn3) : 0;
  const int n = p / 3;

  // ---- T14 prefetch of pointwise epilogue streams (issued before staging)
  uint4 qacc{}, qm{}, qm4{};
  float4 fi0a{}, fi0b{}, fmka{}, fmkb{};
  if (!ismask) {
    if (MODE == M_F0) {
      const float* p0 = in0 + (size_t)p * PLANE + erow;
      fi0a = ((const float4*)p0)[0];
      fi0b = ((const float4*)p0)[1];
      const float* pk = inm + (size_t)n * PLANE + erow;
      fmka = ((const float4*)pk)[0];
      fmkb = ((const float4*)pk)[1];
    } else {
      qacc = *(const uint4*)(accP + (size_t)p * PLANE + erow);
      qm = *(const uint4*)(Smk + (size_t)n * PLANE + erow);
      if (MODE == M_LAST)
        qm4 = *(const uint4*)(Gm4p + (size_t)n * PLANE + erow);
    }
  }

  // ---- fill Wb: rows y0-R..y0+63+R (y clamp), cols x0-R8..x0+63+R8 (x clamp)
  {
    const int w = tid >> 6, rs = (tid >> 3) & 7, cs = tid & 7;
#pragma unroll
    for (int ro = 0; ro < VWIN; ro += 64) {
      const int row = ro + (w << 3) + rs;
#pragma unroll
      for (int cb = 0; cb < 2; ++cb) {
        const int ch = (cb << 3) + cs;
        if (row < VWIN && ch < NCH) {
          const int gy = clampi(y0 + row - R, PH - 1);
          const int gx = x0 - R8 + (ch << 3);
          float v[8];
          if (MODE == M_F0) {
            if (!ismask) { // D0 = img1 - img0 staged on the fly
              const float* r0 = in0 + (size_t)p * PLANE + (size_t)gy * PW;
              const float* r1 = in1 + (size_t)p * PLANE + (size_t)gy * PW;
              if (!edge || (gx >= 0 && gx <= PW - 8)) {
                float a[8], bb[8];
                ff2f8(((const float4*)(r0 + gx))[0],
                      ((const float4*)(r0 + gx))[1], a);
                ff2f8(((const float4*)(r1 + gx))[0],
                      ((const float4*)(r1 + gx))[1], bb);
#pragma unroll
                for (int j = 0; j < 8; ++j) v[j] = bb[j] - a[j];
              } else {
#pragma unroll
                for (int j = 0; j < 8; ++j) {
                  const int cx = clampi(gx + j, PW - 1);
                  v[j] = r1[cx] - r0[cx];
                }
              }
            } else {
              const float* rm = inm + (size_t)pm * PLANE + (size_t)gy * PW;
              if (!edge || (gx >= 0 && gx <= PW - 8)) {
                ff2f8(((const float4*)(rm + gx))[0],
                      ((const float4*)(rm + gx))[1], v);
              } else {
#pragma unroll
                for (int j = 0; j < 8; ++j) v[j] = rm[clampi(gx + j, PW - 1)];
              }
            }
          } else {
            const ushort* sp =
                (ismask ? Smk + (size_t)pm * PLANE : Sc + (size_t)p * PLANE) +
                (size_t)gy * PW;
            if (!edge || (gx >= 0 && gx <= PW - 8)) {
              q2f8(*(const uint4*)&sp[gx], v);
            } else {
#pragma unroll
              for (int j = 0; j < 8; ++j) v[j] = h2f(sp[clampi(gx + j, PW - 1)]);
            }
          }
          float* d = &Wb[row * WSTR + (ch << 3)];
#pragma unroll
          for (int k = 0; k < 4; ++k)
            *(float2*)&d[2 * k] = make_float2(v[2 * k], v[2 * k + 1]);
        }
      }
    }
  }
  __syncthreads();

  // ---- H conv: Wb rows -> Hb (stride 67: 2-way free writes/reads) ----
  {
    const int cg = tid & 7;
    constexpr int basep = R8 - R; // even -> b64-aligned window reads
#pragma unroll
    for (int ro = 0; ro < VWIN; ro += 64) {
      const int r = ro + (tid >> 3);
      if (r < VWIN) {
        const float* wr = &Wb[r * WSTR + basep + (cg << 3)];
        float a[8];
#pragma unroll
        for (int i = 0; i < 8; ++i) a[i] = 0.f;
#pragma unroll
        for (int j2 = 0; j2 < R + 4; ++j2) {
          const float2 v2 = *(const float2*)&wr[2 * j2];
          const int j0 = 2 * j2, j1 = 2 * j2 + 1;
#pragma unroll
          for (int i = 0; i < 8; ++i) {
            if (i <= j0 && j0 - i <= 2 * R)
              a[i] = fmaf(WT.w[j0 - i], v2.x, a[i]);
            if (i <= j1 && j1 - i <= 2 * R)
              a[i] = fmaf(WT.w[j1 - i], v2.y, a[i]);
          }
        }
        float* hr = &Hb[r * 67 + (cg << 3)];
#pragma unroll
        for (int i = 0; i < 8; ++i) hr[i] = a[i];
      }
    }
  }
  __syncthreads();

  // ---- V conv: 8 consecutive rows at column `lane` ----
  const int lane = tid & 63, yg = tid >> 6;
  float b[8];
#pragma unroll
  for (int i = 0; i < 8; ++i) b[i] = 0.f;
#pragma unroll
  for (int j = 0; j < 2 * R + 8; ++j) {
    const float v = Hb[((yg << 3) + j) * 67 + lane];
#pragma unroll
    for (int i = 0; i < 8; ++i)
      if (i <= j && j - i <= 2 * R) b[i] = fmaf(WT.w[j - i], v, b[i]);
  }
  __syncthreads(); // all V reads done -> Hb reusable as transpose stash
#pragma unroll
  for (int i = 0; i < 8; ++i) Hb[lane * 65 + (yg << 3) + i] = b[i];
  __syncthreads();
  float bs[8];
#pragma unroll
  for (int j = 0; j < 8; ++j) bs[j] = Hb[(exq + j) * 65 + ey];

  if (ismask) {
    sth8(oM + (size_t)pm * PLANE + erow, bs);
    return;
  }

  // D at the output pixel = center of the staged window (no global re-read)
  float D[8];
#pragma unroll
  for (int j = 0; j < 8; ++j) D[j] = Wb[(R + ey) * WSTR + R8 + exq + j];

  if (MODE == M_F0) {
    float i0v[8], mv[8], av[8];
    ff2f8(fi0a, fi0b, i0v);
    ff2f8(fmka, fmkb, mv);
#pragma unroll
    for (int j = 0; j < 8; ++j) av[j] = i0v[j] + mv[j] * (D[j] - bs[j]);
    sth8(accP + (size_t)p * PLANE + erow, av);
    sth8(oS + (size_t)p * PLANE + erow, bs);
  } else if (MODE == M_MID) {
    float av[8], mv[8];
    q2f8(qacc, av);
    q2f8(qm, mv);
#pragma unroll
    for (int j = 0; j < 8; ++j) av[j] += mv[j] * (D[j] - bs[j]);
    sth8(accP + (size_t)p * PLANE + erow, av);
    sth8(oS + (size_t)p * PLANE + erow, bs);
  } else { // M_LAST: out = acc + Gm3*(D3 - D4) + Gm4*D4
    float av[8], m3[8], m4[8], o[8];
    q2f8(qacc, av);
    q2f8(qm, m3);
    q2f8(qm4, m4);
#pragma unroll
    for (int j = 0; j < 8; ++j)
      o[j] = av[j] + m3[j] * (D[j] - bs[j]) + m4[j] * bs[j];
    stf8(outp + (size_t)p * PLANE + erow, o);
  }
}

// ---------------- host -----------------------------------------------------
extern "C" void kernel_launch(void* const* d_in, const int* in_sizes, int n_in,
                              void* d_out, int out_size, void* d_ws,
                              size_t ws_size, hipStream_t stream) {
  const float* img0 = (const float*)d_in[0];
  const float* img1 = (const float*)d_in[1];
  const float* mask = (const float*)d_in[2];
  float* out = (float*)d_out;

  const int NTOT = 16;
  // ws half-planes/img (f16): S_A(4) + S_B(4) + acc(3) = 11
  const size_t perImg = (size_t)11 * PLANE * sizeof(ushort);
  int CN = 16;
  while (CN > 1 && (size_t)CN * perImg > ws_size) CN >>= 1;

  for (int s = 0; s < NTOT; s += CN) {
    ushort* SA = (ushort*)d_ws; // [D:3CN][m:CN]
    ushort* SB = SA + (size_t)4 * CN * PLANE;
    ushort* acc = SB + (size_t)4 * CN * PLANE; // 3CN planes
    ushort* SAm = SA + (size_t)3 * CN * PLANE;
    ushort* SBm = SB + (size_t)3 * CN * PLANE;

    const float* in0 = img0 + (size_t)s * 3 * PLANE;
    const float* in1 = img1 + (size_t)s * 3 * PLANE;
    const float* inm = mask + (size_t)s * PLANE;
    float* o = out + (size_t)s * 3 * PLANE;

    const int cn3 = 3 * CN;
    const dim3 blk(512);
    const int gAll = 4 * CN * 64, gD = 3 * CN * 64, gM = CN * 64;
    const ushort* nb = nullptr;
    const float* nf = nullptr;

    // L0: acc = i0 + m*(D0-D1); SA.D = D1; SA.m = Gm1
    hipLaunchKernelGGL((fused_lvl<0, 6, M_F0>), dim3(gAll), blk, 0, stream, nb,
                       nb, nb, in0, in1, inm, SA, SAm, acc, (float*)nullptr,
                       cn3);
    // L1: acc += Gm1*(D1-D2); SB.D = D2; SB.m = Gm2
    hipLaunchKernelGGL((fused_lvl<1, 10, M_MID>), dim3(gAll), blk, 0, stream,
                       SA, SAm, nb, nf, nf, nf, SB, SBm, acc, (float*)nullptr,
                       cn3);
    // L2: acc += Gm2*(D2-D3); SA.D = D3; SA.m = Gm3
    hipLaunchKernelGGL((fused_lvl<2, 18, M_MID>), dim3(gAll), blk, 0, stream,
                       SB, SBm, nb, nf, nf, nf, SA, SAm, acc, (float*)nullptr,
                       cn3);
    // L3a: Gm4 = blur(Gm3) -> SB.m
    hipLaunchKernelGGL((fused_lvl<3, 22, M_MONLY>), dim3(gM), blk, 0, stream,
                       nb, SAm, nb, nf, nf, nf, (ushort*)nullptr, SBm,
                       (ushort*)nullptr, (float*)nullptr, cn3);
    // L3b: out = acc + Gm3*(D3-D4) + Gm4*D4
    hipLaunchKernelGGL((fused_lvl<3, 22, M_LAST>), dim3(gD), blk, 0, stream, SA,
                       SAm, SBm, nf, nf, nf, (ushort*)nullptr,
                       (ushort*)nullptr, acc, o, cn3);
  }
}